// Round 22
// baseline (635.921 us; speedup 1.0000x reference)
//
#include <hip/hip_runtime.h>
#include <cstddef>

#define NN 50000
#define TT 12
#define HH 128
#define EE 800000

typedef short v8s __attribute__((ext_vector_type(8)));
typedef float v4f __attribute__((ext_vector_type(4)));
#define MFMA(a, b, c) __builtin_amdgcn_mfma_f32_16x16x32_bf16(a, b, c, 0, 0, 0)

__device__ __forceinline__ unsigned short f2bf(float f) {
  unsigned int u = __float_as_uint(f);
  u += 0x7FFF + ((u >> 16) & 1);
  return (unsigned short)(u >> 16);
}
__device__ __forceinline__ float bf2f(unsigned short b) {
  return __uint_as_float(((unsigned int)b) << 16);
}
__device__ __forceinline__ unsigned int cvt_pk_bf16(float a, float b) {
  unsigned int r;
  asm("v_cvt_pk_bf16_f32 %0, %1, %2" : "=v"(r) : "v"(a), "v"(b));
  return r;
}
__device__ __forceinline__ float frcp(float x) {
  return __builtin_amdgcn_rcpf(x);
}

// ---- pass 1: ONE u64 atomic per edge (blocks < 3125); remaining blocks do
// the x->bf16 conversion (independent work, saves a launch).
__global__ void k_degposx(const int* __restrict__ ei, const float* __restrict__ ew,
                          unsigned long long* __restrict__ deg64,
                          int* __restrict__ pose,
                          const float* __restrict__ x, unsigned short* __restrict__ xb) {
  if (blockIdx.x < 3125) {
    int e = blockIdx.x * 256 + threadIdx.x;
    if (e >= EE) return;
    int d = ei[EE + e];
    unsigned long long fixw = (unsigned long long)(ew[e] * 4294967296.0f);
    unsigned long long old = atomicAdd(&deg64[d], (1ULL << 40) | fixw);
    pose[e] = (int)(old >> 40);
    return;
  }
  int i = (blockIdx.x - 3125) * 256 + threadIdx.x;  // NN*48 float4 groups
  if (i >= NN * 48) return;
  int n = i / 48, j = (i % 48) * 4;
  float4 v = *(const float4*)&x[(size_t)n * 192 + j];
  ushort4 o;
  o.x = f2bf(v.x); o.y = f2bf(v.y); o.z = f2bf(v.z); o.w = f2bf(v.w);
  *(ushort4*)&xb[(size_t)n * 192 + j] = o;
}

__global__ void k_degpos(const int* __restrict__ ei, const float* __restrict__ ew,
                         unsigned long long* __restrict__ deg64,
                         int* __restrict__ pose) {
  int e = blockIdx.x * 256 + threadIdx.x;
  if (e >= EE) return;
  int d = ei[EE + e];
  unsigned long long fixw = (unsigned long long)(ew[e] * 4294967296.0f);
  unsigned long long old = atomicAdd(&deg64[d], (1ULL << 40) | fixw);
  pose[e] = (int)(old >> 40);
}

// ---- parallel scan, stage A: per-block partial sums + dinv (196 blocks)
__global__ void k_scanA(const unsigned long long* __restrict__ deg64,
                        float* __restrict__ dinv, int* __restrict__ partial) {
  __shared__ int red[256];
  int t = threadIdx.x;
  int n = blockIdx.x * 256 + t;
  int c = 0;
  if (n < NN) {
    unsigned long long v = deg64[n];
    c = (int)(v >> 40);
    float sw = (float)(v & 0xFFFFFFFFFFULL) * (1.0f / 4294967296.0f) + 1.0f;
    dinv[n] = rsqrtf(sw);  // self-loop weight 1 included
  }
  red[t] = c;
  __syncthreads();
  for (int off = 128; off > 0; off >>= 1) {
    if (t < off) red[t] += red[t + off];
    __syncthreads();
  }
  if (t == 0) partial[blockIdx.x] = red[0];
}

// ---- stage B: scan the 196 partials (1 block); partial[b] becomes exclusive base
__global__ void k_scanB(int* __restrict__ partial, int* __restrict__ row) {
  __shared__ int ps[256];
  int t = threadIdx.x;
  int v = (t < 196) ? partial[t] : 0;
  ps[t] = v;
  __syncthreads();
  for (int off = 1; off < 256; off <<= 1) {
    int u = (t >= off) ? ps[t - off] : 0;
    __syncthreads();
    ps[t] += u;
    __syncthreads();
  }
  if (t < 196) partial[t] = ps[t] - v;  // exclusive base
  if (t == 195) row[NN] = ps[t];        // total edge count
}

// ---- stage C: per-node row offsets via block-local scan + base (196 blocks)
__global__ void k_scanC(const unsigned long long* __restrict__ deg64,
                        const int* __restrict__ partial, int* __restrict__ row) {
  __shared__ int ps[256];
  int t = threadIdx.x;
  int n = blockIdx.x * 256 + t;
  int c = (n < NN) ? (int)(deg64[n] >> 40) : 0;
  ps[t] = c;
  __syncthreads();
  for (int off = 1; off < 256; off <<= 1) {
    int u = (t >= off) ? ps[t - off] : 0;
    __syncthreads();
    ps[t] += u;
    __syncthreads();
  }
  if (n < NN) row[n] = partial[blockIdx.x] + ps[t] - c;
}

// pass 2 (+ fused weight prep): atomic-FREE scatter. Blocks 0..3124 scatter;
// blocks 3125..3148 do prep. csr: low16=src, hi16=bf16 w.
__global__ void k_scatprep(const int* __restrict__ ei, const float* __restrict__ ew,
                           const float* __restrict__ dinv, const int* __restrict__ row,
                           const int* __restrict__ pose, unsigned int* __restrict__ csrp,
                           const float* __restrict__ czw, const float* __restrict__ czb,
                           const float* __restrict__ lzw, const float* __restrict__ lzb,
                           const float* __restrict__ crw, const float* __restrict__ crb,
                           const float* __restrict__ lrw, const float* __restrict__ lrb,
                           const float* __restrict__ chw, const float* __restrict__ chb,
                           const float* __restrict__ lhw, const float* __restrict__ lhb,
                           float* __restrict__ A, float* __restrict__ bfv) {
  if (blockIdx.x < 3125) {
    int e = blockIdx.x * 256 + threadIdx.x;
    if (e >= EE) return;
    int s = ei[e], d = ei[EE + e];
    float nrm = dinv[s] * ew[e] * dinv[d];
    csrp[row[d] + pose[e]] = (unsigned int)s | ((unsigned int)f2bf(nrm) << 16);
    return;
  }
  int pb = blockIdx.x - 3125;
  int g = pb >> 3, ch = pb & 7;
  const float *cw, *cb, *lw, *lb;
  if (g == 0)      { cw = czw; cb = czb; lw = lzw; lb = lzb; }
  else if (g == 1) { cw = crw; cb = crb; lw = lrw; lb = lrb; }
  else             { cw = chw; cb = chb; lw = lhw; lb = lhb; }
  float* Ao = A + g * 2048;
  float* bo = bfv + g * 128;
  int idx = ch * 256 + threadIdx.x;
  int f = idx >> 7, j = idx & 127;
  float acc = 0.f;
  for (int k = 0; k < 128; k++) acc = fmaf(cw[f * 128 + k], lw[k * 128 + j], acc);
  Ao[idx] = acc;
  if (ch == 0 && threadIdx.x < 128) {
    int jj = threadIdx.x;
    float a2 = lb[jj];
    for (int k = 0; k < 128; k++) a2 = fmaf(cb[k], lw[k * 128 + jj], a2);
    bo[jj] = a2;
  }
}

// single-pass gather over bf16 x: 384B/neighbor (3 coalesced 128B lines).
__global__ void k_gather_bf(const int* __restrict__ row, const unsigned int* __restrict__ csrp,
                            const float* __restrict__ dinv,
                            const unsigned short* __restrict__ xb,
                            unsigned short* __restrict__ Ybf) {
  int d = blockIdx.x * 4 + (threadIdx.x >> 6);
  if (d >= NN) return;
  int lane = threadIdx.x & 63;
  float acc0, acc1, acc2;
  {
    float dv = dinv[d]; dv *= dv;  // self loop
    const unsigned short* xr = xb + (size_t)d * 192;
    acc0 = dv * bf2f(xr[lane]);
    acc1 = dv * bf2f(xr[lane + 64]);
    acc2 = dv * bf2f(xr[lane + 128]);
  }
  int kb = row[d], ke = row[d + 1];
  int n = ke - kb;
  const unsigned int* cp = csrp + kb;
  unsigned int e0 = 0, e1 = 0, e2 = 0;
  unsigned short a0 = 0, b0 = 0, c0 = 0, a1 = 0, b1 = 0, c1 = 0;
  if (n > 0) e0 = cp[0];
  if (n > 1) e1 = cp[1];
  if (n > 0) {
    const unsigned short* s = xb + (size_t)(e0 & 0xFFFF) * 192;
    a0 = s[lane]; b0 = s[lane + 64]; c0 = s[lane + 128];
  }
  if (n > 1) {
    const unsigned short* s = xb + (size_t)(e1 & 0xFFFF) * 192;
    a1 = s[lane]; b1 = s[lane + 64]; c1 = s[lane + 128];
  }
  for (int k = 0; k < n; k++) {
    if (k + 2 < n) e2 = cp[k + 2];
    float wv = bf2f((unsigned short)(e0 >> 16));
    acc0 = fmaf(wv, bf2f(a0), acc0);
    acc1 = fmaf(wv, bf2f(b0), acc1);
    acc2 = fmaf(wv, bf2f(c0), acc2);
    e0 = e1; a0 = a1; b0 = b1; c0 = c1; e1 = e2;
    if (k + 2 < n) {
      const unsigned short* s = xb + (size_t)(e2 & 0xFFFF) * 192;
      a1 = s[lane]; b1 = s[lane + 64]; c1 = s[lane + 128];
    }
  }
  int c, t, f;
  c = lane;       t = c % TT; f = c / TT; Ybf[((size_t)t * NN + d) * 16 + f] = f2bf(acc0);
  c = lane + 64;  t = c % TT; f = c / TT; Ybf[((size_t)t * NN + d) * 16 + f] = f2bf(acc1);
  c = lane + 128; t = c % TT; f = c / TT; Ybf[((size_t)t * NN + d) * 16 + f] = f2bf(acc2);
}

// fallback: single-pass gather over fp32 x
__global__ void k_gather_f32(const int* __restrict__ row, const unsigned int* __restrict__ csrp,
                             const float* __restrict__ dinv,
                             const float* __restrict__ x, unsigned short* __restrict__ Ybf) {
  int d = blockIdx.x * 4 + (threadIdx.x >> 6);
  if (d >= NN) return;
  int lane = threadIdx.x & 63;
  float acc0, acc1, acc2;
  {
    float dv = dinv[d]; dv *= dv;  // self loop
    const float* xr = x + (size_t)d * 192;
    acc0 = dv * xr[lane]; acc1 = dv * xr[lane + 64]; acc2 = dv * xr[lane + 128];
  }
  int kb = row[d], ke = row[d + 1];
  int n = ke - kb;
  const unsigned int* cp = csrp + kb;
  unsigned int e0 = 0, e1 = 0, e2 = 0;
  float a0 = 0, b0 = 0, c0 = 0, a1 = 0, b1 = 0, c1 = 0;
  if (n > 0) e0 = cp[0];
  if (n > 1) e1 = cp[1];
  if (n > 0) {
    const float* s = x + (size_t)(e0 & 0xFFFF) * 192;
    a0 = s[lane]; b0 = s[lane + 64]; c0 = s[lane + 128];
  }
  if (n > 1) {
    const float* s = x + (size_t)(e1 & 0xFFFF) * 192;
    a1 = s[lane]; b1 = s[lane + 64]; c1 = s[lane + 128];
  }
  for (int k = 0; k < n; k++) {
    if (k + 2 < n) e2 = cp[k + 2];
    float wv = bf2f((unsigned short)(e0 >> 16));
    acc0 = fmaf(wv, a0, acc0);
    acc1 = fmaf(wv, b0, acc1);
    acc2 = fmaf(wv, c0, acc2);
    e0 = e1; a0 = a1; b0 = b1; c0 = c1; e1 = e2;
    if (k + 2 < n) {
      const float* s = x + (size_t)(e2 & 0xFFFF) * 192;
      a1 = s[lane]; b1 = s[lane + 64]; c1 = s[lane + 128];
    }
  }
  int c, t, f;
  c = lane;       t = c % TT; f = c / TT; Ybf[((size_t)t * NN + d) * 16 + f] = f2bf(acc0);
  c = lane + 64;  t = c % TT; f = c / TT; Ybf[((size_t)t * NN + d) * 16 + f] = f2bf(acc1);
  c = lane + 128; t = c % TT; f = c / TT; Ybf[((size_t)t * NN + d) * 16 + f] = f2bf(acc2);
}

// ---------------- main fused GRU + attention + output (MFMA) ----------------
// R22 BISECT: body is R20/R18 VERBATIM (proven numerics); the ONLY change is
// __launch_bounds__(512,3) replacing (512,1)+waves_per_eu(2). This isolates
// whether the 3-blocks/CU register cap (~84, forces spills of the 108-reg
// demand) is the shared cause of R19/R21's NaNs. If PASS: cap is safe, bug
// was Lb/zpk. If NaN: abandon the occupancy chase, revert to R20.
__global__ __launch_bounds__(512, 3) void k_main(
    const unsigned short* __restrict__ Ybf, const float* __restrict__ A,
    const float* __restrict__ bfv,
    const float* __restrict__ lzw, const float* __restrict__ lrw, const float* __restrict__ lhw,
    const float* __restrict__ a1w, const float* __restrict__ a1b,
    const float* __restrict__ a2w, const float* __restrict__ a2b,
    const float* __restrict__ ow, const float* __restrict__ ob,
    float* __restrict__ out) {
  const int HS = 136, YS = 40;
  __shared__ __align__(16) unsigned char smem[47360];
  unsigned short* h_hi = (unsigned short*)smem;                  // 17408
  unsigned short* u_hi = (unsigned short*)(smem + 17408);        // 17408
  unsigned short* y_db = (unsigned short*)(smem + 34816);        // 2 x 5120
  float* sc = (float*)(smem + 45056);                            // 2304
  float* ctxb = (float*)smem;            // epilogue alias (34816)
  float* owb  = (float*)(smem + 34816);  // epilogue alias (8192)

  const int tid = threadIdx.x;
  const int w = tid >> 6;
  const int lane = tid & 63;
  const int ln = lane & 15;
  const int lg = lane >> 4;
  const int kg = 8 * lg;
  const int cw = 16 * w + ln;
  const int co = 16 * w + 4 * lg;
  const int base = blockIdx.x * 64;

  for (int i = tid; i < 64 * 136; i += 512) h_hi[i] = 0;
  for (int i = tid; i < 2 * 64 * 40; i += 512) {
    if ((i % YS) >= 16) y_db[i] = 0;
  }

  v8s whZ[4], whR[4], whH[4], waA[4];
  v8s afZ, afR, afH;
#pragma unroll
  for (int ks = 0; ks < 4; ks++) {
#pragma unroll
    for (int j = 0; j < 8; j++) {
      int krow = 128 + 32 * ks + kg + j;
      whZ[ks][j] = (short)f2bf(lzw[krow * HH + cw]);
      whR[ks][j] = (short)f2bf(lrw[krow * HH + cw]);
      whH[ks][j] = (short)f2bf(lhw[krow * HH + cw]);
      waA[ks][j] = (short)f2bf(a1w[(32 * ks + kg + j) * HH + cw]);
    }
  }
#pragma unroll
  for (int j = 0; j < 8; j++) {
    int f = (kg + j) & 15;
    afZ[j] = (lg < 2) ? (short)f2bf(A[f * HH + cw]) : (short)0;
    afR[j] = (lg < 2) ? (short)f2bf(A[2048 + f * HH + cw]) : (short)0;
    afH[j] = (lg < 2) ? (short)f2bf(A[4096 + f * HH + cw]) : (short)0;
  }

  const float4 bz4 = *(const float4*)&bfv[co];
  const float4 br4 = *(const float4*)&bfv[128 + co];
  const float4 bh4 = *(const float4*)&bfv[256 + co];
  const float4 ab4 = *(const float4*)&a1b[co];
  const float4 a2v = *(const float4*)&a2w[co];
  const float b2 = a2b[0];

  v4f ctx[4], az[4], ar[4], hn[4];
  float mrun[4], srun[4];
#pragma unroll
  for (int nt = 0; nt < 4; nt++) {
    ctx[nt] = (v4f){0.f, 0.f, 0.f, 0.f};
    hn[nt] = (v4f){0.f, 0.f, 0.f, 0.f};
    mrun[nt] = -1e30f; srun[nt] = 0.f;
  }
  const int yrw = tid >> 3, yfp = (tid & 7) * 2;
  const int ygr = base + yrw;
  {
    unsigned int v = 0;
    if (ygr < NN) v = *(const unsigned int*)&Ybf[(size_t)ygr * 16 + yfp];
    *(unsigned int*)&y_db[yrw * YS + yfp] = v;
  }
  __syncthreads();

  for (int t = 0; t < TT; t++) {
    const unsigned short* ycur = y_db + (t & 1) * 2560;
    unsigned short* ynxt = y_db + ((t + 1) & 1) * 2560;
    if (t < TT - 1) {
      unsigned int v = 0;
      if (ygr < NN) v = *(const unsigned int*)&Ybf[((size_t)(t + 1) * NN + ygr) * 16 + yfp];
      *(unsigned int*)&ynxt[yrw * YS + yfp] = v;
    }

    // ---- fused phase A+B: gates + score + u = h*r (no internal barrier) ----
#pragma unroll
    for (int nt = 0; nt < 4; nt++) {
      const int hb = (16 * nt + ln) * HS;
      v8s yf = *(const v8s*)&ycur[(16 * nt + ln) * YS + kg];
      v4f za = (v4f){bz4.x, bz4.y, bz4.z, bz4.w};
      v4f ra = (v4f){br4.x, br4.y, br4.z, br4.w};
      v4f ga = (v4f){ab4.x, ab4.y, ab4.z, ab4.w};
      za = MFMA(afZ, yf, za);
      ra = MFMA(afR, yf, ra);
#pragma unroll
      for (int ks = 0; ks < 4; ks++) {  // three independent accumulator chains
        v8s hf = *(const v8s*)&h_hi[hb + 32 * ks + kg];
        za = MFMA(whZ[ks], hf, za);
        ra = MFMA(whR[ks], hf, ra);
        ga = MFMA(waA[ks], hf, ga);
      }
      az[nt] = za;
      ar[nt] = ra;
      float pp = fmaxf(ga[0], 0.f) * a2v.x + fmaxf(ga[1], 0.f) * a2v.y +
                 fmaxf(ga[2], 0.f) * a2v.z + fmaxf(ga[3], 0.f) * a2v.w;
      pp += __shfl_xor(pp, 16, 64);
      pp += __shfl_xor(pp, 32, 64);
      if (lane < 16) sc[(16 * nt + lane) * 9 + w] = pp;
      // u = h*r -> own u_hi cells (registers + own cells: no hazard with A)
      const int idx = hb + co;
      float u0 = hn[nt][0] * frcp(1.f + __expf(-ra[0]));
      float u1 = hn[nt][1] * frcp(1.f + __expf(-ra[1]));
      float u2 = hn[nt][2] * frcp(1.f + __expf(-ra[2]));
      float u3 = hn[nt][3] * frcp(1.f + __expf(-ra[3]));
      *(uint2*)&u_hi[idx] = make_uint2(cvt_pk_bf16(u0, u1), cvt_pk_bf16(u2, u3));
    }
    __syncthreads();  // u_hi + sc visible

    // ---- phase C: candidate gate + softmax(ctx with OLD hn) + h_new ----
#pragma unroll
    for (int nt = 0; nt < 4; nt++) {
      const int hb = (16 * nt + ln) * HS;
      v8s yf = *(const v8s*)&ycur[(16 * nt + ln) * YS + kg];
      v4f acch = (v4f){bh4.x, bh4.y, bh4.z, bh4.w};
      acch = MFMA(afH, yf, acch);
#pragma unroll
      for (int ks = 0; ks < 4; ks++) {
        v8s uf = *(const v8s*)&u_hi[hb + 32 * ks + kg];
        acch = MFMA(whH[ks], uf, acch);
      }
      if (t > 0) {  // score(h_{t-1}) pairs with hn = h_{t-1} (pre-overwrite)
        const float* sr = &sc[(16 * nt + ln) * 9];
        float e = b2 + sr[0] + sr[1] + sr[2] + sr[3] + sr[4] + sr[5] + sr[6] + sr[7];
        float mn = fmaxf(mrun[nt], e);
        float al = __expf(mrun[nt] - mn);
        float be = __expf(e - mn);
        srun[nt] = srun[nt] * al + be;
        mrun[nt] = mn;
#pragma unroll
        for (int r = 0; r < 4; r++) ctx[nt][r] = ctx[nt][r] * al + be * hn[nt][r];
      }
#pragma unroll
      for (int r = 0; r < 4; r++) {
        float zz = frcp(1.f + __expf(-az[nt][r]));
        float th = 2.f * frcp(1.f + __expf(-2.f * acch[r])) - 1.f;
        hn[nt][r] = zz * hn[nt][r] + (1.f - zz) * th;
      }
      const int idx = hb + co;
      *(uint2*)&h_hi[idx] = make_uint2(cvt_pk_bf16(hn[nt][0], hn[nt][1]),
                                       cvt_pk_bf16(hn[nt][2], hn[nt][3]));
    }
    __syncthreads();  // h_new + y_{t+1} visible for next iteration
  }

  // ---- final attention pass for h_12 (in regs) ----
  {
#pragma unroll
    for (int nt = 0; nt < 4; nt++) {
      const int hb = (16 * nt + ln) * HS;
      v4f ga = (v4f){ab4.x, ab4.y, ab4.z, ab4.w};
#pragma unroll
      for (int ks = 0; ks < 4; ks++) {
        v8s hf = *(const v8s*)&h_hi[hb + 32 * ks + kg];
        ga = MFMA(waA[ks], hf, ga);
      }
      float pp = fmaxf(ga[0], 0.f) * a2v.x + fmaxf(ga[1], 0.f) * a2v.y +
                 fmaxf(ga[2], 0.f) * a2v.z + fmaxf(ga[3], 0.f) * a2v.w;
      pp += __shfl_xor(pp, 16, 64);
      pp += __shfl_xor(pp, 32, 64);
      if (lane < 16) sc[(16 * nt + lane) * 9 + w] = pp;
    }
    __syncthreads();
#pragma unroll
    for (int nt = 0; nt < 4; nt++) {
      const float* sr = &sc[(16 * nt + ln) * 9];
      float e = b2 + sr[0] + sr[1] + sr[2] + sr[3] + sr[4] + sr[5] + sr[6] + sr[7];
      float mn = fmaxf(mrun[nt], e);
      float al = __expf(mrun[nt] - mn);
      float be = __expf(e - mn);
      srun[nt] = srun[nt] * al + be;
#pragma unroll
      for (int r = 0; r < 4; r++) ctx[nt][r] = ctx[nt][r] * al + be * hn[nt][r];
    }
  }
  __syncthreads();

#pragma unroll
  for (int nt = 0; nt < 4; nt++) {
    float inv = frcp(srun[nt]);
    *(float4*)&ctxb[(16 * nt + ln) * 136 + co] =
        make_float4(ctx[nt][0] * inv, ctx[nt][1] * inv, ctx[nt][2] * inv, ctx[nt][3] * inv);
  }
  for (int i = tid; i < 2048; i += 512) owb[i] = ow[i];
  __syncthreads();
#pragma unroll
  for (int pp = 0; pp < 2; pp++) {
    int idx = tid + pp * 512;
    int n = idx >> 4, o = idx & 15;
    float acc = ob[o];
    const float* cr = &ctxb[n * 136];
#pragma unroll 8
    for (int c = 0; c < 128; c++) acc = fmaf(cr[c], owb[c * 16 + o], acc);
    int gn = base + n;
    if (gn < NN) out[gn * 16 + o] = acc;
  }
}

extern "C" void kernel_launch(void* const* d_in, const int* in_sizes, int n_in,
                              void* d_out, int out_size, void* d_ws, size_t ws_size,
                              hipStream_t stream) {
  const float* x   = (const float*)d_in[0];
  const int*   ei  = (const int*)d_in[1];
  const float* ew  = (const float*)d_in[2];
  const float* czw = (const float*)d_in[3],  *czb = (const float*)d_in[4];
  const float* crw = (const float*)d_in[5],  *crb = (const float*)d_in[6];
  const float* chw = (const float*)d_in[7],  *chb = (const float*)d_in[8];
  const float* lzw = (const float*)d_in[9],  *lzb = (const float*)d_in[10];
  const float* lrw = (const float*)d_in[11], *lrb = (const float*)d_in[12];
  const float* lhw = (const float*)d_in[13], *lhb = (const float*)d_in[14];
  const float* a1w = (const float*)d_in[15], *a1b = (const float*)d_in[16];
  const float* a2w = (const float*)d_in[17], *a2b = (const float*)d_in[18];
  const float* ow  = (const float*)d_in[19], *ob  = (const float*)d_in[20];

  float* ws = (float*)d_ws;
  unsigned long long* deg64 = (unsigned long long*)ws;        // N u64 -> 100096 f
  float* dinv = ws + 100096;                                  // N f32 -> 150144
  int*   row  = (int*)(ws + 150144);                          // N+1   -> 200576
  int*   pose = (int*)(ws + 200576);                          // E int -> 1000576
  unsigned int* csrp = (unsigned int*)(ws + 1000576);         // E     -> 1800576
  float* A    = ws + 1800576;                                 // 6144  -> 1806720
  float* bfv  = ws + 1806720;                                 // 384   -> 1807104
  int* partial = (int*)(ws + 1807104);                        // 256   -> 1807360
  unsigned short* Ybf = (unsigned short*)(ws + 1807360);      // 9.6M us -> 6607360
  unsigned short* xb  = (unsigned short*)(ws + 6607360);      // 9.6M us -> 11407360
  float* out = (float*)d_out;

  const bool big_ws = ws_size >= (size_t)11407360 * 4;  // 45.6 MB bf16-x path

  hipMemsetAsync(deg64, 0, NN * sizeof(unsigned long long), stream);
  if (big_ws) {
    k_degposx<<<12500, 256, 0, stream>>>(ei, ew, deg64, pose, x, xb);
  } else {
    k_degpos<<<3125, 256, 0, stream>>>(ei, ew, deg64, pose);
  }
  k_scanA<<<196, 256, 0, stream>>>(deg64, dinv, partial);
  k_scanB<<<1, 256, 0, stream>>>(partial, row);
  k_scanC<<<196, 256, 0, stream>>>(deg64, partial, row);
  k_scatprep<<<3149, 256, 0, stream>>>(ei, ew, dinv, row, pose, csrp,
                                       czw, czb, lzw, lzb, crw, crb, lrw, lrb,
                                       chw, chb, lhw, lhb, A, bfv);
  if (big_ws) {
    k_gather_bf<<<12500, 256, 0, stream>>>(row, csrp, dinv, xb, Ybf);
  } else {
    k_gather_f32<<<12500, 256, 0, stream>>>(row, csrp, dinv, x, Ybf);
  }
  k_main<<<782, 512, 0, stream>>>(Ybf, A, bfv, lzw, lrw, lhw,
                                  a1w, a1b, a2w, a2b, ow, ob, out);
}

// Round 23
// 398.511 us; speedup vs baseline: 1.5957x; 1.5957x over previous
//
#include <hip/hip_runtime.h>
#include <cstddef>

#define NN 50000
#define TT 12
#define HH 128
#define EE 800000

typedef short v8s __attribute__((ext_vector_type(8)));
typedef float v4f __attribute__((ext_vector_type(4)));
#define MFMA(a, b, c) __builtin_amdgcn_mfma_f32_16x16x32_bf16(a, b, c, 0, 0, 0)

__device__ __forceinline__ unsigned short f2bf(float f) {
  unsigned int u = __float_as_uint(f);
  u += 0x7FFF + ((u >> 16) & 1);
  return (unsigned short)(u >> 16);
}
__device__ __forceinline__ float bf2f(unsigned short b) {
  return __uint_as_float(((unsigned int)b) << 16);
}
__device__ __forceinline__ unsigned int cvt_pk_bf16(float a, float b) {
  unsigned int r;
  asm("v_cvt_pk_bf16_f32 %0, %1, %2" : "=v"(r) : "v"(a), "v"(b));
  return r;
}
__device__ __forceinline__ float frcp(float x) {
  return __builtin_amdgcn_rcpf(x);
}

// ---- pass 1: ONE u64 atomic per edge (blocks < 3125); remaining blocks do
// the x->bf16 conversion (independent work, saves a launch).
__global__ void k_degposx(const int* __restrict__ ei, const float* __restrict__ ew,
                          unsigned long long* __restrict__ deg64,
                          int* __restrict__ pose,
                          const float* __restrict__ x, unsigned short* __restrict__ xb) {
  if (blockIdx.x < 3125) {
    int e = blockIdx.x * 256 + threadIdx.x;
    if (e >= EE) return;
    int d = ei[EE + e];
    unsigned long long fixw = (unsigned long long)(ew[e] * 4294967296.0f);
    unsigned long long old = atomicAdd(&deg64[d], (1ULL << 40) | fixw);
    pose[e] = (int)(old >> 40);
    return;
  }
  int i = (blockIdx.x - 3125) * 256 + threadIdx.x;  // NN*48 float4 groups
  if (i >= NN * 48) return;
  int n = i / 48, j = (i % 48) * 4;
  float4 v = *(const float4*)&x[(size_t)n * 192 + j];
  ushort4 o;
  o.x = f2bf(v.x); o.y = f2bf(v.y); o.z = f2bf(v.z); o.w = f2bf(v.w);
  *(ushort4*)&xb[(size_t)n * 192 + j] = o;
}

__global__ void k_degpos(const int* __restrict__ ei, const float* __restrict__ ew,
                         unsigned long long* __restrict__ deg64,
                         int* __restrict__ pose) {
  int e = blockIdx.x * 256 + threadIdx.x;
  if (e >= EE) return;
  int d = ei[EE + e];
  unsigned long long fixw = (unsigned long long)(ew[e] * 4294967296.0f);
  unsigned long long old = atomicAdd(&deg64[d], (1ULL << 40) | fixw);
  pose[e] = (int)(old >> 40);
}

// ---- parallel scan, stage A: per-block partial sums + dinv (196 blocks)
__global__ void k_scanA(const unsigned long long* __restrict__ deg64,
                        float* __restrict__ dinv, int* __restrict__ partial) {
  __shared__ int red[256];
  int t = threadIdx.x;
  int n = blockIdx.x * 256 + t;
  int c = 0;
  if (n < NN) {
    unsigned long long v = deg64[n];
    c = (int)(v >> 40);
    float sw = (float)(v & 0xFFFFFFFFFFULL) * (1.0f / 4294967296.0f) + 1.0f;
    dinv[n] = rsqrtf(sw);  // self-loop weight 1 included
  }
  red[t] = c;
  __syncthreads();
  for (int off = 128; off > 0; off >>= 1) {
    if (t < off) red[t] += red[t + off];
    __syncthreads();
  }
  if (t == 0) partial[blockIdx.x] = red[0];
}

// ---- stage B: scan the 196 partials (1 block); partial[b] becomes exclusive base
__global__ void k_scanB(int* __restrict__ partial, int* __restrict__ row) {
  __shared__ int ps[256];
  int t = threadIdx.x;
  int v = (t < 196) ? partial[t] : 0;
  ps[t] = v;
  __syncthreads();
  for (int off = 1; off < 256; off <<= 1) {
    int u = (t >= off) ? ps[t - off] : 0;
    __syncthreads();
    ps[t] += u;
    __syncthreads();
  }
  if (t < 196) partial[t] = ps[t] - v;  // exclusive base
  if (t == 195) row[NN] = ps[t];        // total edge count
}

// ---- stage C: per-node row offsets via block-local scan + base (196 blocks)
__global__ void k_scanC(const unsigned long long* __restrict__ deg64,
                        const int* __restrict__ partial, int* __restrict__ row) {
  __shared__ int ps[256];
  int t = threadIdx.x;
  int n = blockIdx.x * 256 + t;
  int c = (n < NN) ? (int)(deg64[n] >> 40) : 0;
  ps[t] = c;
  __syncthreads();
  for (int off = 1; off < 256; off <<= 1) {
    int u = (t >= off) ? ps[t - off] : 0;
    __syncthreads();
    ps[t] += u;
    __syncthreads();
  }
  if (n < NN) row[n] = partial[blockIdx.x] + ps[t] - c;
}

// pass 2 (+ fused weight prep): atomic-FREE scatter. Blocks 0..3124 scatter;
// blocks 3125..3148 do prep. csr: low16=src, hi16=bf16 w.
__global__ void k_scatprep(const int* __restrict__ ei, const float* __restrict__ ew,
                           const float* __restrict__ dinv, const int* __restrict__ row,
                           const int* __restrict__ pose, unsigned int* __restrict__ csrp,
                           const float* __restrict__ czw, const float* __restrict__ czb,
                           const float* __restrict__ lzw, const float* __restrict__ lzb,
                           const float* __restrict__ crw, const float* __restrict__ crb,
                           const float* __restrict__ lrw, const float* __restrict__ lrb,
                           const float* __restrict__ chw, const float* __restrict__ chb,
                           const float* __restrict__ lhw, const float* __restrict__ lhb,
                           float* __restrict__ A, float* __restrict__ bfv) {
  if (blockIdx.x < 3125) {
    int e = blockIdx.x * 256 + threadIdx.x;
    if (e >= EE) return;
    int s = ei[e], d = ei[EE + e];
    float nrm = dinv[s] * ew[e] * dinv[d];
    csrp[row[d] + pose[e]] = (unsigned int)s | ((unsigned int)f2bf(nrm) << 16);
    return;
  }
  int pb = blockIdx.x - 3125;
  int g = pb >> 3, ch = pb & 7;
  const float *cw, *cb, *lw, *lb;
  if (g == 0)      { cw = czw; cb = czb; lw = lzw; lb = lzb; }
  else if (g == 1) { cw = crw; cb = crb; lw = lrw; lb = lrb; }
  else             { cw = chw; cb = chb; lw = lhw; lb = lhb; }
  float* Ao = A + g * 2048;
  float* bo = bfv + g * 128;
  int idx = ch * 256 + threadIdx.x;
  int f = idx >> 7, j = idx & 127;
  float acc = 0.f;
  for (int k = 0; k < 128; k++) acc = fmaf(cw[f * 128 + k], lw[k * 128 + j], acc);
  Ao[idx] = acc;
  if (ch == 0 && threadIdx.x < 128) {
    int jj = threadIdx.x;
    float a2 = lb[jj];
    for (int k = 0; k < 128; k++) a2 = fmaf(cb[k], lw[k * 128 + jj], a2);
    bo[jj] = a2;
  }
}

// single-pass gather over bf16 x: 384B/neighbor (3 coalesced 128B lines).
__global__ void k_gather_bf(const int* __restrict__ row, const unsigned int* __restrict__ csrp,
                            const float* __restrict__ dinv,
                            const unsigned short* __restrict__ xb,
                            unsigned short* __restrict__ Ybf) {
  int d = blockIdx.x * 4 + (threadIdx.x >> 6);
  if (d >= NN) return;
  int lane = threadIdx.x & 63;
  float acc0, acc1, acc2;
  {
    float dv = dinv[d]; dv *= dv;  // self loop
    const unsigned short* xr = xb + (size_t)d * 192;
    acc0 = dv * bf2f(xr[lane]);
    acc1 = dv * bf2f(xr[lane + 64]);
    acc2 = dv * bf2f(xr[lane + 128]);
  }
  int kb = row[d], ke = row[d + 1];
  int n = ke - kb;
  const unsigned int* cp = csrp + kb;
  unsigned int e0 = 0, e1 = 0, e2 = 0;
  unsigned short a0 = 0, b0 = 0, c0 = 0, a1 = 0, b1 = 0, c1 = 0;
  if (n > 0) e0 = cp[0];
  if (n > 1) e1 = cp[1];
  if (n > 0) {
    const unsigned short* s = xb + (size_t)(e0 & 0xFFFF) * 192;
    a0 = s[lane]; b0 = s[lane + 64]; c0 = s[lane + 128];
  }
  if (n > 1) {
    const unsigned short* s = xb + (size_t)(e1 & 0xFFFF) * 192;
    a1 = s[lane]; b1 = s[lane + 64]; c1 = s[lane + 128];
  }
  for (int k = 0; k < n; k++) {
    if (k + 2 < n) e2 = cp[k + 2];
    float wv = bf2f((unsigned short)(e0 >> 16));
    acc0 = fmaf(wv, bf2f(a0), acc0);
    acc1 = fmaf(wv, bf2f(b0), acc1);
    acc2 = fmaf(wv, bf2f(c0), acc2);
    e0 = e1; a0 = a1; b0 = b1; c0 = c1; e1 = e2;
    if (k + 2 < n) {
      const unsigned short* s = xb + (size_t)(e2 & 0xFFFF) * 192;
      a1 = s[lane]; b1 = s[lane + 64]; c1 = s[lane + 128];
    }
  }
  int c, t, f;
  c = lane;       t = c % TT; f = c / TT; Ybf[((size_t)t * NN + d) * 16 + f] = f2bf(acc0);
  c = lane + 64;  t = c % TT; f = c / TT; Ybf[((size_t)t * NN + d) * 16 + f] = f2bf(acc1);
  c = lane + 128; t = c % TT; f = c / TT; Ybf[((size_t)t * NN + d) * 16 + f] = f2bf(acc2);
}

// fallback: single-pass gather over fp32 x
__global__ void k_gather_f32(const int* __restrict__ row, const unsigned int* __restrict__ csrp,
                             const float* __restrict__ dinv,
                             const float* __restrict__ x, unsigned short* __restrict__ Ybf) {
  int d = blockIdx.x * 4 + (threadIdx.x >> 6);
  if (d >= NN) return;
  int lane = threadIdx.x & 63;
  float acc0, acc1, acc2;
  {
    float dv = dinv[d]; dv *= dv;  // self loop
    const float* xr = x + (size_t)d * 192;
    acc0 = dv * xr[lane]; acc1 = dv * xr[lane + 64]; acc2 = dv * xr[lane + 128];
  }
  int kb = row[d], ke = row[d + 1];
  int n = ke - kb;
  const unsigned int* cp = csrp + kb;
  unsigned int e0 = 0, e1 = 0, e2 = 0;
  float a0 = 0, b0 = 0, c0 = 0, a1 = 0, b1 = 0, c1 = 0;
  if (n > 0) e0 = cp[0];
  if (n > 1) e1 = cp[1];
  if (n > 0) {
    const float* s = x + (size_t)(e0 & 0xFFFF) * 192;
    a0 = s[lane]; b0 = s[lane + 64]; c0 = s[lane + 128];
  }
  if (n > 1) {
    const float* s = x + (size_t)(e1 & 0xFFFF) * 192;
    a1 = s[lane]; b1 = s[lane + 64]; c1 = s[lane + 128];
  }
  for (int k = 0; k < n; k++) {
    if (k + 2 < n) e2 = cp[k + 2];
    float wv = bf2f((unsigned short)(e0 >> 16));
    acc0 = fmaf(wv, a0, acc0);
    acc1 = fmaf(wv, b0, acc1);
    acc2 = fmaf(wv, c0, acc2);
    e0 = e1; a0 = a1; b0 = b1; c0 = c1; e1 = e2;
    if (k + 2 < n) {
      const float* s = x + (size_t)(e2 & 0xFFFF) * 192;
      a1 = s[lane]; b1 = s[lane + 64]; c1 = s[lane + 128];
    }
  }
  int c, t, f;
  c = lane;       t = c % TT; f = c / TT; Ybf[((size_t)t * NN + d) * 16 + f] = f2bf(acc0);
  c = lane + 64;  t = c % TT; f = c / TT; Ybf[((size_t)t * NN + d) * 16 + f] = f2bf(acc1);
  c = lane + 128; t = c % TT; f = c / TT; Ybf[((size_t)t * NN + d) * 16 + f] = f2bf(acc2);
}

// ---------------- main fused GRU + attention + output (MFMA) ----------------
// FINAL (R20 config): 2 barriers/t, u_hi separate buffer, h bf16 operand-cache
// with authoritative fp32 register state, double-buffered y, persistent bf16
// weight fragments. (512,1)+waves_per_eu(2) = 2 blocks/CU, VGPR 108, no spill.
// Occupancy chase closed by measurement: (512,3) cap -> 106MB spills, 2x
// slower, occupancy unchanged (scratch blocks residency); the reg-diet
// transforms (bias->LDS, packed-z) NaN'd twice unexplained -> quarantined.
__global__ __launch_bounds__(512, 1) __attribute__((amdgpu_waves_per_eu(2)))
void k_main(
    const unsigned short* __restrict__ Ybf, const float* __restrict__ A,
    const float* __restrict__ bfv,
    const float* __restrict__ lzw, const float* __restrict__ lrw, const float* __restrict__ lhw,
    const float* __restrict__ a1w, const float* __restrict__ a1b,
    const float* __restrict__ a2w, const float* __restrict__ a2b,
    const float* __restrict__ ow, const float* __restrict__ ob,
    float* __restrict__ out) {
  const int HS = 136, YS = 40;
  __shared__ __align__(16) unsigned char smem[47360];
  unsigned short* h_hi = (unsigned short*)smem;                  // 17408
  unsigned short* u_hi = (unsigned short*)(smem + 17408);        // 17408
  unsigned short* y_db = (unsigned short*)(smem + 34816);        // 2 x 5120
  float* sc = (float*)(smem + 45056);                            // 2304
  float* ctxb = (float*)smem;            // epilogue alias (34816)
  float* owb  = (float*)(smem + 34816);  // epilogue alias (8192)

  const int tid = threadIdx.x;
  const int w = tid >> 6;
  const int lane = tid & 63;
  const int ln = lane & 15;
  const int lg = lane >> 4;
  const int kg = 8 * lg;
  const int cw = 16 * w + ln;
  const int co = 16 * w + 4 * lg;
  const int base = blockIdx.x * 64;

  for (int i = tid; i < 64 * 136; i += 512) h_hi[i] = 0;
  for (int i = tid; i < 2 * 64 * 40; i += 512) {
    if ((i % YS) >= 16) y_db[i] = 0;
  }

  v8s whZ[4], whR[4], whH[4], waA[4];
  v8s afZ, afR, afH;
#pragma unroll
  for (int ks = 0; ks < 4; ks++) {
#pragma unroll
    for (int j = 0; j < 8; j++) {
      int krow = 128 + 32 * ks + kg + j;
      whZ[ks][j] = (short)f2bf(lzw[krow * HH + cw]);
      whR[ks][j] = (short)f2bf(lrw[krow * HH + cw]);
      whH[ks][j] = (short)f2bf(lhw[krow * HH + cw]);
      waA[ks][j] = (short)f2bf(a1w[(32 * ks + kg + j) * HH + cw]);
    }
  }
#pragma unroll
  for (int j = 0; j < 8; j++) {
    int f = (kg + j) & 15;
    afZ[j] = (lg < 2) ? (short)f2bf(A[f * HH + cw]) : (short)0;
    afR[j] = (lg < 2) ? (short)f2bf(A[2048 + f * HH + cw]) : (short)0;
    afH[j] = (lg < 2) ? (short)f2bf(A[4096 + f * HH + cw]) : (short)0;
  }

  const float4 bz4 = *(const float4*)&bfv[co];
  const float4 br4 = *(const float4*)&bfv[128 + co];
  const float4 bh4 = *(const float4*)&bfv[256 + co];
  const float4 ab4 = *(const float4*)&a1b[co];
  const float4 a2v = *(const float4*)&a2w[co];
  const float b2 = a2b[0];

  v4f ctx[4], az[4], ar[4], hn[4];
  float mrun[4], srun[4];
#pragma unroll
  for (int nt = 0; nt < 4; nt++) {
    ctx[nt] = (v4f){0.f, 0.f, 0.f, 0.f};
    hn[nt] = (v4f){0.f, 0.f, 0.f, 0.f};
    mrun[nt] = -1e30f; srun[nt] = 0.f;
  }
  const int yrw = tid >> 3, yfp = (tid & 7) * 2;
  const int ygr = base + yrw;
  {
    unsigned int v = 0;
    if (ygr < NN) v = *(const unsigned int*)&Ybf[(size_t)ygr * 16 + yfp];
    *(unsigned int*)&y_db[yrw * YS + yfp] = v;
  }
  __syncthreads();

  for (int t = 0; t < TT; t++) {
    const unsigned short* ycur = y_db + (t & 1) * 2560;
    unsigned short* ynxt = y_db + ((t + 1) & 1) * 2560;
    if (t < TT - 1) {
      unsigned int v = 0;
      if (ygr < NN) v = *(const unsigned int*)&Ybf[((size_t)(t + 1) * NN + ygr) * 16 + yfp];
      *(unsigned int*)&ynxt[yrw * YS + yfp] = v;
    }

    // ---- fused phase A+B: gates + score + u = h*r (no internal barrier) ----
#pragma unroll
    for (int nt = 0; nt < 4; nt++) {
      const int hb = (16 * nt + ln) * HS;
      v8s yf = *(const v8s*)&ycur[(16 * nt + ln) * YS + kg];
      v4f za = (v4f){bz4.x, bz4.y, bz4.z, bz4.w};
      v4f ra = (v4f){br4.x, br4.y, br4.z, br4.w};
      v4f ga = (v4f){ab4.x, ab4.y, ab4.z, ab4.w};
      za = MFMA(afZ, yf, za);
      ra = MFMA(afR, yf, ra);
#pragma unroll
      for (int ks = 0; ks < 4; ks++) {  // three independent accumulator chains
        v8s hf = *(const v8s*)&h_hi[hb + 32 * ks + kg];
        za = MFMA(whZ[ks], hf, za);
        ra = MFMA(whR[ks], hf, ra);
        ga = MFMA(waA[ks], hf, ga);
      }
      az[nt] = za;
      ar[nt] = ra;
      float pp = fmaxf(ga[0], 0.f) * a2v.x + fmaxf(ga[1], 0.f) * a2v.y +
                 fmaxf(ga[2], 0.f) * a2v.z + fmaxf(ga[3], 0.f) * a2v.w;
      pp += __shfl_xor(pp, 16, 64);
      pp += __shfl_xor(pp, 32, 64);
      if (lane < 16) sc[(16 * nt + lane) * 9 + w] = pp;
      // u = h*r -> own u_hi cells (registers + own cells: no hazard with A)
      const int idx = hb + co;
      float u0 = hn[nt][0] * frcp(1.f + __expf(-ra[0]));
      float u1 = hn[nt][1] * frcp(1.f + __expf(-ra[1]));
      float u2 = hn[nt][2] * frcp(1.f + __expf(-ra[2]));
      float u3 = hn[nt][3] * frcp(1.f + __expf(-ra[3]));
      *(uint2*)&u_hi[idx] = make_uint2(cvt_pk_bf16(u0, u1), cvt_pk_bf16(u2, u3));
    }
    __syncthreads();  // u_hi + sc visible

    // ---- phase C: candidate gate + softmax(ctx with OLD hn) + h_new ----
#pragma unroll
    for (int nt = 0; nt < 4; nt++) {
      const int hb = (16 * nt + ln) * HS;
      v8s yf = *(const v8s*)&ycur[(16 * nt + ln) * YS + kg];
      v4f acch = (v4f){bh4.x, bh4.y, bh4.z, bh4.w};
      acch = MFMA(afH, yf, acch);
#pragma unroll
      for (int ks = 0; ks < 4; ks++) {
        v8s uf = *(const v8s*)&u_hi[hb + 32 * ks + kg];
        acch = MFMA(whH[ks], uf, acch);
      }
      if (t > 0) {  // score(h_{t-1}) pairs with hn = h_{t-1} (pre-overwrite)
        const float* sr = &sc[(16 * nt + ln) * 9];
        float e = b2 + sr[0] + sr[1] + sr[2] + sr[3] + sr[4] + sr[5] + sr[6] + sr[7];
        float mn = fmaxf(mrun[nt], e);
        float al = __expf(mrun[nt] - mn);
        float be = __expf(e - mn);
        srun[nt] = srun[nt] * al + be;
        mrun[nt] = mn;
#pragma unroll
        for (int r = 0; r < 4; r++) ctx[nt][r] = ctx[nt][r] * al + be * hn[nt][r];
      }
#pragma unroll
      for (int r = 0; r < 4; r++) {
        float zz = frcp(1.f + __expf(-az[nt][r]));
        float th = 2.f * frcp(1.f + __expf(-2.f * acch[r])) - 1.f;
        hn[nt][r] = zz * hn[nt][r] + (1.f - zz) * th;
      }
      const int idx = hb + co;
      *(uint2*)&h_hi[idx] = make_uint2(cvt_pk_bf16(hn[nt][0], hn[nt][1]),
                                       cvt_pk_bf16(hn[nt][2], hn[nt][3]));
    }
    __syncthreads();  // h_new + y_{t+1} visible for next iteration
  }

  // ---- final attention pass for h_12 (in regs) ----
  {
#pragma unroll
    for (int nt = 0; nt < 4; nt++) {
      const int hb = (16 * nt + ln) * HS;
      v4f ga = (v4f){ab4.x, ab4.y, ab4.z, ab4.w};
#pragma unroll
      for (int ks = 0; ks < 4; ks++) {
        v8s hf = *(const v8s*)&h_hi[hb + 32 * ks + kg];
        ga = MFMA(waA[ks], hf, ga);
      }
      float pp = fmaxf(ga[0], 0.f) * a2v.x + fmaxf(ga[1], 0.f) * a2v.y +
                 fmaxf(ga[2], 0.f) * a2v.z + fmaxf(ga[3], 0.f) * a2v.w;
      pp += __shfl_xor(pp, 16, 64);
      pp += __shfl_xor(pp, 32, 64);
      if (lane < 16) sc[(16 * nt + lane) * 9 + w] = pp;
    }
    __syncthreads();
#pragma unroll
    for (int nt = 0; nt < 4; nt++) {
      const float* sr = &sc[(16 * nt + ln) * 9];
      float e = b2 + sr[0] + sr[1] + sr[2] + sr[3] + sr[4] + sr[5] + sr[6] + sr[7];
      float mn = fmaxf(mrun[nt], e);
      float al = __expf(mrun[nt] - mn);
      float be = __expf(e - mn);
      srun[nt] = srun[nt] * al + be;
#pragma unroll
      for (int r = 0; r < 4; r++) ctx[nt][r] = ctx[nt][r] * al + be * hn[nt][r];
    }
  }
  __syncthreads();

#pragma unroll
  for (int nt = 0; nt < 4; nt++) {
    float inv = frcp(srun[nt]);
    *(float4*)&ctxb[(16 * nt + ln) * 136 + co] =
        make_float4(ctx[nt][0] * inv, ctx[nt][1] * inv, ctx[nt][2] * inv, ctx[nt][3] * inv);
  }
  for (int i = tid; i < 2048; i += 512) owb[i] = ow[i];
  __syncthreads();
#pragma unroll
  for (int pp = 0; pp < 2; pp++) {
    int idx = tid + pp * 512;
    int n = idx >> 4, o = idx & 15;
    float acc = ob[o];
    const float* cr = &ctxb[n * 136];
#pragma unroll 8
    for (int c = 0; c < 128; c++) acc = fmaf(cr[c], owb[c * 16 + o], acc);
    int gn = base + n;
    if (gn < NN) out[gn * 16 + o] = acc;
  }
}

extern "C" void kernel_launch(void* const* d_in, const int* in_sizes, int n_in,
                              void* d_out, int out_size, void* d_ws, size_t ws_size,
                              hipStream_t stream) {
  const float* x   = (const float*)d_in[0];
  const int*   ei  = (const int*)d_in[1];
  const float* ew  = (const float*)d_in[2];
  const float* czw = (const float*)d_in[3],  *czb = (const float*)d_in[4];
  const float* crw = (const float*)d_in[5],  *crb = (const float*)d_in[6];
  const float* chw = (const float*)d_in[7],  *chb = (const float*)d_in[8];
  const float* lzw = (const float*)d_in[9],  *lzb = (const float*)d_in[10];
  const float* lrw = (const float*)d_in[11], *lrb = (const float*)d_in[12];
  const float* lhw = (const float*)d_in[13], *lhb = (const float*)d_in[14];
  const float* a1w = (const float*)d_in[15], *a1b = (const float*)d_in[16];
  const float* a2w = (const float*)d_in[17], *a2b = (const float*)d_in[18];
  const float* ow  = (const float*)d_in[19], *ob  = (const float*)d_in[20];

  float* ws = (float*)d_ws;
  unsigned long long* deg64 = (unsigned long long*)ws;        // N u64 -> 100096 f
  float* dinv = ws + 100096;                                  // N f32 -> 150144
  int*   row  = (int*)(ws + 150144);                          // N+1   -> 200576
  int*   pose = (int*)(ws + 200576);                          // E int -> 1000576
  unsigned int* csrp = (unsigned int*)(ws + 1000576);         // E     -> 1800576
  float* A    = ws + 1800576;                                 // 6144  -> 1806720
  float* bfv  = ws + 1806720;                                 // 384   -> 1807104
  int* partial = (int*)(ws + 1807104);                        // 256   -> 1807360
  unsigned short* Ybf = (unsigned short*)(ws + 1807360);      // 9.6M us -> 6607360
  unsigned short* xb  = (unsigned short*)(ws + 6607360);      // 9.6M us -> 11407360
  float* out = (float*)d_out;

  const bool big_ws = ws_size >= (size_t)11407360 * 4;  // 45.6 MB bf16-x path

  hipMemsetAsync(deg64, 0, NN * sizeof(unsigned long long), stream);
  if (big_ws) {
    k_degposx<<<12500, 256, 0, stream>>>(ei, ew, deg64, pose, x, xb);
  } else {
    k_degpos<<<3125, 256, 0, stream>>>(ei, ew, deg64, pose);
  }
  k_scanA<<<196, 256, 0, stream>>>(deg64, dinv, partial);
  k_scanB<<<1, 256, 0, stream>>>(partial, row);
  k_scanC<<<196, 256, 0, stream>>>(deg64, partial, row);
  k_scatprep<<<3149, 256, 0, stream>>>(ei, ew, dinv, row, pose, csrp,
                                       czw, czb, lzw, lzb, crw, crb, lrw, lrb,
                                       chw, chb, lhw, lhb, A, bfv);
  if (big_ws) {
    k_gather_bf<<<12500, 256, 0, stream>>>(row, csrp, dinv, xb, Ybf);
  } else {
    k_gather_f32<<<12500, 256, 0, stream>>>(row, csrp, dinv, x, Ybf);
  }
  k_main<<<782, 512, 0, stream>>>(Ybf, A, bfv, lzw, lrw, lhw,
                                  a1w, a1b, a2w, a2b, ow, ob, out);
}